// Round 11
// baseline (270.505 us; speedup 1.0000x reference)
//
#include <hip/hip_runtime.h>
#include <cstdint>
#include <cstddef>

#define N_INST 200
#define HWPIX (448 * 448)        // 200704 pixels per mask
#define W64 3136                 // uint64 words per packed mask
#define SIGMA 2.0f
#define NCHUNK 8                 // K-split factor in pair kernel
#define NTILE 325                // triangular 8x8 tiles over a 25x25 tile grid

// workspace layout (bytes)
#define P_SLAB  (N_INST * N_INST)              // ints per partial-count slab
#define OFF_P   5017600                        // after packed (200*3136*8)
#define OFF_SP  (OFF_P + NCHUNK * P_SLAB * 4)  // per-chunk per-mask popcounts

// native clang vector (HIP's uint4 is a class — rejected by
// __builtin_nontemporal_load; ext_vector_type is accepted)
typedef unsigned int uint4v __attribute__((ext_vector_type(4)));

// ---------------------------------------------------------------------------
// K1: bitpack, MLP=16, NON-TEMPORAL loads (input is stream-once; nt keeps the
// 4.8 MiB packed array L2-resident for K2 instead of being evicted by 160 MB
// of dead input). Input is exactly {0.0f, 1.0f} -> integer !=0 test is exact.
// Fixed pixel permutation (exact for AND/popcount):
//   word w = bx*64 + t, bit 4s+q  <-  pixel bx*4096 + s*256 + t*4 + q.
// ---------------------------------------------------------------------------
__global__ void __launch_bounds__(64)
pack_kernel(const uint32_t* __restrict__ seg, uint64_t* __restrict__ packed) {
    const int t = threadIdx.x;                 // 0..63
    const uint4v* s4 = (const uint4v*)(seg + (size_t)blockIdx.y * HWPIX
                                           + (size_t)blockIdx.x * 4096);
    uint4v v[16];
#pragma unroll
    for (int s = 0; s < 16; ++s)
        v[s] = __builtin_nontemporal_load(&s4[s * 64 + t]);  // 16 in flight
    uint64_t m = 0;
#pragma unroll
    for (int s = 0; s < 16; ++s) {
        uint32_t b = 0;
        b |= v[s].x ? 1u : 0u;
        b |= v[s].y ? 2u : 0u;
        b |= v[s].z ? 4u : 0u;
        b |= v[s].w ? 8u : 0u;
        m |= (uint64_t)b << (4 * s);
    }
    packed[(size_t)blockIdx.y * W64 + blockIdx.x * 64 + t] = m;
}

// ---------------------------------------------------------------------------
// K2: pairwise intersection counts, 8x8 tile per wave, K-split by NCHUNK=8.
// 325 tiles x 8 chunks = 2600 waves. Off-diagonal -> P[chunk][j][i];
// diagonal (i==j) -> SP[chunk][i] (per-mask popcounts for free, no atomics).
// Wave-sums <= 7 iters * 64 bits * 64 lanes = 28672 < 2^16: counts packed
// 2-per-int -> 32-reg x 6-step butterfly (exact mod 2^32). (R5/R9 config.)
// ---------------------------------------------------------------------------
__global__ void pair_kernel(const uint64_t* __restrict__ packed,
                            int* __restrict__ P,
                            int* __restrict__ SP) {
    const int wt   = blockIdx.x * 4 + (threadIdx.x >> 6);   // 0..2599
    const int lane = threadIdx.x & 63;
    const int t     = wt >> 3;        // tile id 0..324
    const int chunk = wt & 7;

    int jt = (int)((sqrtf((float)(8 * t + 1)) - 1.0f) * 0.5f);
    while ((jt + 1) * (jt + 2) / 2 <= t) ++jt;
    while (jt * (jt + 1) / 2 > t) --jt;
    const int it = t - jt * (jt + 1) / 2;
    const int i0 = 8 * it, j0 = 8 * jt;

    const int ks = (chunk * 49) >> 3;          // 0,6,12,18,24,30,36,42
    const int ke = ((chunk + 1) * 49) >> 3;    // 6,...,42,49

    const uint64_t* A = packed + (size_t)i0 * W64;
    const uint64_t* B = packed + (size_t)j0 * W64;

    int c[64];
#pragma unroll
    for (int x = 0; x < 64; ++x) c[x] = 0;

    for (int kb = ks; kb < ke; ++kb) {
        const int k = kb * 64 + lane;
        uint64_t a[8], b[8];
#pragma unroll
        for (int r = 0; r < 8; ++r) { a[r] = A[k + r * W64]; b[r] = B[k + r * W64]; }
#pragma unroll
        for (int r = 0; r < 8; ++r)
#pragma unroll
            for (int cc = 0; cc < 8; ++cc)
                c[r * 8 + cc] += __popcll(a[r] & b[cc]);
    }

    int p[32];
#pragma unroll
    for (int m = 0; m < 32; ++m) p[m] = c[2 * m] + (c[2 * m + 1] << 16);
#pragma unroll
    for (int off = 1; off < 64; off <<= 1) {
#pragma unroll
        for (int m = 0; m < 32; ++m) p[m] += __shfl_xor(p[m], off, 64);
    }

    if (lane == 0) {
#pragma unroll
        for (int r = 0; r < 8; ++r) {
#pragma unroll
            for (int cc = 0; cc < 8; ++cc) {
                const int idx = r * 8 + cc;
                const int val = (idx & 1) ? (int)(((unsigned)p[idx >> 1]) >> 16)
                                          : (p[idx >> 1] & 0xFFFF);
                const int i = i0 + r, j = j0 + cc;
                if (i < j)       P[chunk * P_SLAB + j * N_INST + i] = val;
                else if (i == j) SP[chunk * 256 + i] = val;   // popc(a&a)=|mask|
            }
        }
    }
}

// ---------------------------------------------------------------------------
// K3: full epilogue in ONE single-block kernel (1024 thr = 16 waves on 1 CU —
// R4's regression used 256 serial row scans; here wave w owns columns
// j in {w, w+16, ...} with lanes splitting i -> coalesced P reads, butterfly
// reduction). Pass A: comp[j] = max_{i<j} d_ij -> LDS. Pass B: recompute d_ij
// from P (1.3 MB L2/L3 re-read, ~2 us; cheaper than a DTf round-trip + extra
// launch) and out[j] = scores[j]*exp(SIGMA*min_i(comp_i^2 - d_ij^2)).
// (min of exp == exp of min; d_ij = 0 for i >= j or label mismatch.)
// ---------------------------------------------------------------------------
__global__ void __launch_bounds__(1024)
epilogue_kernel(const int* __restrict__ P,
                const int* __restrict__ SP,
                const int* __restrict__ labels,
                const float* __restrict__ scores,
                float* __restrict__ out) {
    __shared__ float ssum[N_INST];
    __shared__ int   lab[N_INST];
    __shared__ float comp[N_INST];
    const int tid  = threadIdx.x;
    const int wv   = tid >> 6;          // 0..15
    const int lane = tid & 63;

    if (tid < N_INST) {
        int s = 0;
#pragma unroll
        for (int cch = 0; cch < NCHUNK; ++cch) s += SP[cch * 256 + tid];
        ssum[tid] = (float)s;
        lab[tid]  = labels[tid];
    }
    __syncthreads();

    // Pass A: comp[j] = max_{i<j} decay_iou[i][j]
    for (int j = wv; j < N_INST; j += 16) {
        const float sj = ssum[j];
        const int   lj = lab[j];
        float m = 0.0f;
        for (int i = lane; i < j; i += 64) {
            int inter = 0;
#pragma unroll
            for (int cch = 0; cch < NCHUNK; ++cch)
                inter += P[cch * P_SLAB + j * N_INST + i];
            const float iou = (float)inter / (ssum[i] + sj - (float)inter);
            m = fmaxf(m, (lab[i] == lj) ? iou : 0.0f);
        }
#pragma unroll
        for (int off = 1; off < 64; off <<= 1)
            m = fmaxf(m, __shfl_xor(m, off, 64));
        if (lane == 0) comp[j] = m;
    }
    __syncthreads();

    // Pass B: min + exp
    for (int j = wv; j < N_INST; j += 16) {
        const float sj = ssum[j];
        const int   lj = lab[j];
        float mn = 3.4e38f;
        for (int i = lane; i < N_INST; i += 64) {
            const float ci = comp[i];
            float v = ci * ci;
            if (i < j) {
                int inter = 0;
#pragma unroll
                for (int cch = 0; cch < NCHUNK; ++cch)
                    inter += P[cch * P_SLAB + j * N_INST + i];
                const float iou = (float)inter / (ssum[i] + sj - (float)inter);
                const float d = (lab[i] == lj) ? iou : 0.0f;
                v -= d * d;
            }
            mn = fminf(mn, v);
        }
#pragma unroll
        for (int off = 1; off < 64; off <<= 1)
            mn = fminf(mn, __shfl_xor(mn, off, 64));
        if (lane == 0) out[j] = scores[j] * expf(SIGMA * mn);
    }
}

extern "C" void kernel_launch(void* const* d_in, const int* in_sizes, int n_in,
                              void* d_out, int out_size, void* d_ws, size_t ws_size,
                              hipStream_t stream) {
    const uint32_t* seg = (const uint32_t*)d_in[0];  // fp32 {0,1} -> bit test
    const float* scores = (const float*)d_in[1];     // (200,) fp32
    const int*   labels = (const int*)d_in[2];       // (200,) int32
    float* out = (float*)d_out;                      // (200,) fp32

    uint64_t* packed = (uint64_t*)d_ws;
    int*      P      = (int*)((char*)d_ws + OFF_P);
    int*      SP     = (int*)((char*)d_ws + OFF_SP);

    {
        dim3 grid(49, N_INST);
        pack_kernel<<<grid, 64, 0, stream>>>(seg, packed);
    }
    pair_kernel<<<NTILE * NCHUNK / 4, 256, 0, stream>>>(packed, P, SP);
    epilogue_kernel<<<1, 1024, 0, stream>>>(P, SP, labels, scores, out);
}